// Round 1
// baseline (98.683 us; speedup 1.0000x reference)
//
#include <hip/hip_runtime.h>
#include <hip/hip_bf16.h>
#include <math.h>

#define BB 256
#define PP 100
#define EE 32
#define VV 1000
#define HH 256
#define NFF 33
#define F35 35
#define K1 1120  // 35*E

// ---------------- Kernel A: column sums S0, S1 of W1 ----------------
__global__ void k_sums(const float* __restrict__ W1, float* __restrict__ S01) {
    int j = threadIdx.x;  // 256 threads
    const float* row = W1 + j * K1;
    float s0 = 0.f, s1 = 0.f;
#pragma unroll
    for (int e = 0; e < 32; ++e) { s0 += row[e]; s1 += row[32 + e]; }
    S01[j] = s0;
    S01[256 + j] = s1;
}

// ---------------- Kernel B: G[f][v][j] = dot(tables[f,v,:], W1[j, 64+32f : 96+32f]) ----------------
// grid: NFF*8 blocks; block handles (f, chunk of 125 v's); 256 threads (one per j).
__global__ void k_precompute_G(const float* __restrict__ tables,
                               const float* __restrict__ W1,
                               __hip_bfloat16* __restrict__ G) {
    __shared__ float Wlds[32 * 256];  // Wlds[e*256 + j], bank-conflict-free reads across j
    int f = blockIdx.x >> 3;
    int chunk = blockIdx.x & 7;
    int j = threadIdx.x;
    const float* wsrc = W1 + (size_t)j * K1 + 64 + 32 * f;
#pragma unroll
    for (int e = 0; e < 32; ++e) Wlds[e * 256 + j] = wsrc[e];
    __syncthreads();
    int v0 = chunk * 125;
    for (int v = v0; v < v0 + 125; ++v) {
        const float* tr = tables + ((size_t)f * VV + v) * EE;  // lane-uniform -> scalar loads
        float acc = 0.f;
#pragma unroll
        for (int e = 0; e < 32; ++e) acc += tr[e] * Wlds[e * 256 + j];
        G[((size_t)f * VV + v) * HH + j] = __float2bfloat16(acc);
    }
}

// ---------------- Kernel C: main gather-accumulate -> logits ----------------
// grid: B*P blocks, 256 threads (one per hidden channel j).
__global__ void k_main(const float* __restrict__ x,
                       const __hip_bfloat16* __restrict__ G,
                       const float* __restrict__ S01,
                       const float* __restrict__ b1,
                       const float* __restrict__ W2,
                       const float* __restrict__ b2,
                       float* __restrict__ logits) {
    int r = blockIdx.x;  // 0..25599
    int j = threadIdx.x;
    __shared__ int sidx[NFF];
    __shared__ float sx[2];
    __shared__ float red[256];
    const float* xr = x + (size_t)r * F35;
    if (j < 2) sx[j] = xr[j];
    if (j >= 2 && j < F35) sidx[j - 2] = (int)xr[j];
    __syncthreads();
    float acc = b1[j] + sx[0] * S01[j] + sx[1] * S01[256 + j];
#pragma unroll
    for (int f = 0; f < NFF; ++f) {
        acc += __bfloat162float(G[((size_t)f * VV + sidx[f]) * HH + j]);
    }
    float h = fmaxf(acc, 0.f);
    red[j] = h * W2[j];
    __syncthreads();
#pragma unroll
    for (int s = 128; s > 0; s >>= 1) {
        if (j < s) red[j] += red[j + s];
        __syncthreads();
    }
    if (j == 0) logits[r] = red[0] + b2[0];
}

// ---------------- Fallback (small ws): direct fp32 compute of logits ----------------
__global__ void k_direct(const float* __restrict__ x,
                         const float* __restrict__ tables,
                         const float* __restrict__ W1,
                         const float* __restrict__ b1,
                         const float* __restrict__ W2,
                         const float* __restrict__ b2,
                         float* __restrict__ logits) {
    int r = blockIdx.x;
    int j = threadIdx.x;
    __shared__ int sidx[NFF];
    __shared__ float sx[2];
    __shared__ float red[256];
    const float* xr = x + (size_t)r * F35;
    if (j < 2) sx[j] = xr[j];
    if (j >= 2 && j < F35) sidx[j - 2] = (int)xr[j];
    __syncthreads();
    const float* w = W1 + (size_t)j * K1;
    float acc = b1[j];
    float s0 = 0.f, s1 = 0.f;
#pragma unroll
    for (int e = 0; e < 32; ++e) { s0 += w[e]; s1 += w[32 + e]; }
    acc += sx[0] * s0 + sx[1] * s1;
    for (int f = 0; f < NFF; ++f) {
        const float* tr = tables + ((size_t)f * VV + sidx[f]) * EE;
        const float* wf = w + 64 + 32 * f;
#pragma unroll
        for (int e = 0; e < 32; ++e) acc += tr[e] * wf[e];
    }
    float h = fmaxf(acc, 0.f);
    red[j] = h * W2[j];
    __syncthreads();
#pragma unroll
    for (int s = 128; s > 0; s >>= 1) {
        if (j < s) red[j] += red[j + s];
        __syncthreads();
    }
    if (j == 0) logits[r] = red[0] + b2[0];
}

// ---------------- Kernel D: softmax over P per b (in-place on d_out) ----------------
__global__ void k_softmax(float* __restrict__ io) {
    int b = blockIdx.x;
    int t = threadIdx.x;  // 128
    __shared__ float buf[128];
    float v = (t < PP) ? io[(size_t)b * PP + t] : -INFINITY;
    buf[t] = v;
    __syncthreads();
#pragma unroll
    for (int s = 64; s > 0; s >>= 1) {
        if (t < s) buf[t] = fmaxf(buf[t], buf[t + s]);
        __syncthreads();
    }
    float m = buf[0];
    __syncthreads();
    float e = (t < PP) ? __expf(v - m) : 0.f;
    buf[t] = e;
    __syncthreads();
#pragma unroll
    for (int s = 64; s > 0; s >>= 1) {
        if (t < s) buf[t] += buf[t + s];
        __syncthreads();
    }
    float denom = buf[0];
    if (t < PP) io[(size_t)b * PP + t] = e / denom;
}

extern "C" void kernel_launch(void* const* d_in, const int* in_sizes, int n_in,
                              void* d_out, int out_size, void* d_ws, size_t ws_size,
                              hipStream_t stream) {
    const float* x      = (const float*)d_in[0];
    const float* tables = (const float*)d_in[1];
    const float* W1     = (const float*)d_in[2];
    const float* b1     = (const float*)d_in[3];
    const float* W2     = (const float*)d_in[4];
    const float* b2     = (const float*)d_in[5];
    float* out = (float*)d_out;  // logits staged in-place, then softmax in-place

    const size_t gbytes = (size_t)NFF * VV * HH * sizeof(__hip_bfloat16);  // 16,896,000
    const size_t need = gbytes + 2048;

    if (ws_size >= need) {
        char* ws = (char*)d_ws;
        __hip_bfloat16* G = (__hip_bfloat16*)ws;
        float* S01 = (float*)(ws + gbytes);
        hipLaunchKernelGGL(k_sums, dim3(1), dim3(256), 0, stream, W1, S01);
        hipLaunchKernelGGL(k_precompute_G, dim3(NFF * 8), dim3(256), 0, stream, tables, W1, G);
        hipLaunchKernelGGL(k_main, dim3(BB * PP), dim3(256), 0, stream,
                           x, G, S01, b1, W2, b2, out);
    } else {
        hipLaunchKernelGGL(k_direct, dim3(BB * PP), dim3(256), 0, stream,
                           x, tables, W1, b1, W2, b2, out);
    }
    hipLaunchKernelGGL(k_softmax, dim3(BB), dim3(128), 0, stream, out);
}

// Round 2
// 54.169 us; speedup vs baseline: 1.8218x; 1.8218x over previous
//
#include <hip/hip_runtime.h>
#include <hip/hip_bf16.h>
#include <math.h>

#define BB 256
#define PP 100
#define EE 32
#define VV 1000
#define HH 256
#define NFF 33
#define F35 35
#define K1 1120  // 35*E
#define GSCALE 64.0f
#define GINV 0.015625f

// fp8 hw conversion availability
#define FP8_HW 0
#if defined(__has_builtin)
#if __has_builtin(__builtin_amdgcn_cvt_pk_f32_fp8) && __has_builtin(__builtin_amdgcn_cvt_pk_fp8_f32)
#undef FP8_HW
#define FP8_HW 1
#endif
#endif

#if FP8_HW
typedef float v2f __attribute__((ext_vector_type(2)));
#endif

__device__ __forceinline__ unsigned char enc_fp8(float x) {
#if FP8_HW
    int pk = __builtin_amdgcn_cvt_pk_fp8_f32(x, 0.f, 0, false);
    return (unsigned char)(pk & 0xFF);
#else
    float a = fabsf(x);
    unsigned int s = (x < 0.f) ? 0x80u : 0u;
    if (a >= 448.f) return (unsigned char)(s | 0x7E);
    if (a < 0.015625f) {  // subnormal, step 2^-9
        int m = (int)rintf(a * 512.f);
        if (m > 7) return (unsigned char)(s | 0x08);
        return (unsigned char)(s | (unsigned int)m);
    }
    unsigned int u = __float_as_uint(a);
    u += 0x00080000u;  // round at 3-mantissa-bit boundary
    int e = (int)(u >> 23) - 127 + 7;
    if (e >= 16) return (unsigned char)(s | 0x7E);
    return (unsigned char)(s | ((unsigned int)e << 3) | ((u >> 20) & 7));
#endif
}

#if !FP8_HW
__device__ __forceinline__ float dec1(unsigned int b) {
    unsigned int s = b >> 7, e = (b >> 3) & 15, m = b & 7;
    float v = e ? __uint_as_float(((e + 120u) << 23) | (m << 20))
                : (float)m * 0.001953125f;
    return s ? -v : v;
}
#endif

// ---------------- Kernel: precompute G (fp8, scaled) + S01 sums ----------------
// blocks 0..NFF*25-1: (f, chunk of 40 v). block NFF*25: column sums S0,S1.
__global__ void k_pre(const float* __restrict__ tables, const float* __restrict__ W1,
                      unsigned char* __restrict__ G, float* __restrict__ S01) {
    if (blockIdx.x == NFF * 25) {
        int j = threadIdx.x;
        const float* row = W1 + (size_t)j * K1;
        float s0 = 0.f, s1 = 0.f;
#pragma unroll
        for (int e = 0; e < 32; ++e) { s0 += row[e]; s1 += row[32 + e]; }
        S01[j] = s0;
        S01[256 + j] = s1;
        return;
    }
    __shared__ float Wlds[32 * 256];
    int f = blockIdx.x / 25;
    int chunk = blockIdx.x % 25;
    int j = threadIdx.x;
    const float* wsrc = W1 + (size_t)j * K1 + 64 + 32 * f;
#pragma unroll
    for (int e = 0; e < 32; ++e) Wlds[e * 256 + j] = wsrc[e];
    __syncthreads();
    int v0 = chunk * 40;
    for (int v = v0; v < v0 + 40; ++v) {
        const float* tr = tables + ((size_t)f * VV + v) * EE;  // wave-uniform
        float acc = 0.f;
#pragma unroll
        for (int e = 0; e < 32; ++e) acc += tr[e] * Wlds[e * 256 + j];
        G[((size_t)f * VV + v) * HH + j] = enc_fp8(acc * GSCALE);
    }
}

// ---------------- Main: one wave per row, lane l owns j=4l..4l+3 ----------------
__global__ __launch_bounds__(256) void k_main(const float* __restrict__ x,
                                              const unsigned char* __restrict__ G,
                                              const float* __restrict__ S01,
                                              const float* __restrict__ b1,
                                              const float* __restrict__ W2,
                                              const float* __restrict__ b2,
                                              float* __restrict__ logits) {
    int lane = threadIdx.x & 63;
    int wave = threadIdx.x >> 6;
    int r = blockIdx.x * 4 + wave;  // row id 0..25599
    const float* xr = x + (size_t)r * F35;
    float xv = (lane < F35) ? xr[lane] : 0.f;
    int xi = (int)xv;
    float x0 = __uint_as_float(__builtin_amdgcn_readlane(__float_as_uint(xv), 0));
    float x1 = __uint_as_float(__builtin_amdgcn_readlane(__float_as_uint(xv), 1));

    int j0 = lane * 4;
    float4 s0v = *(const float4*)(S01 + j0);
    float4 s1v = *(const float4*)(S01 + 256 + j0);
    float4 b1v = *(const float4*)(b1 + j0);
    float4 w2v = *(const float4*)(W2 + j0);

    float g0 = 0.f, g1 = 0.f, g2 = 0.f, g3 = 0.f;
#pragma unroll
    for (int f = 0; f < NFF; ++f) {
        int v = __builtin_amdgcn_readlane((unsigned int)xi, 2 + f);  // SGPR index
        const unsigned int* p = (const unsigned int*)(G + ((size_t)f * VV + v) * HH);
        unsigned int u = p[lane];  // sbase + voffset load, 4 fp8
#if FP8_HW
        v2f lo = __builtin_amdgcn_cvt_pk_f32_fp8((int)u, false);
        v2f hi = __builtin_amdgcn_cvt_pk_f32_fp8((int)u, true);
        g0 += lo[0]; g1 += lo[1]; g2 += hi[0]; g3 += hi[1];
#else
        g0 += dec1(u & 255u); g1 += dec1((u >> 8) & 255u);
        g2 += dec1((u >> 16) & 255u); g3 += dec1(u >> 24);
#endif
    }
    float a0 = b1v.x + x0 * s0v.x + x1 * s1v.x + g0 * GINV;
    float a1 = b1v.y + x0 * s0v.y + x1 * s1v.y + g1 * GINV;
    float a2 = b1v.z + x0 * s0v.z + x1 * s1v.z + g2 * GINV;
    float a3 = b1v.w + x0 * s0v.w + x1 * s1v.w + g3 * GINV;
    float part = fmaxf(a0, 0.f) * w2v.x + fmaxf(a1, 0.f) * w2v.y +
                 fmaxf(a2, 0.f) * w2v.z + fmaxf(a3, 0.f) * w2v.w;
#pragma unroll
    for (int m = 32; m > 0; m >>= 1) part += __shfl_xor(part, m, 64);
    if (lane == 0) logits[r] = part + b2[0];
}

// ---------------- Fallback (small ws): direct fp32 compute of logits ----------------
__global__ void k_direct(const float* __restrict__ x,
                         const float* __restrict__ tables,
                         const float* __restrict__ W1,
                         const float* __restrict__ b1,
                         const float* __restrict__ W2,
                         const float* __restrict__ b2,
                         float* __restrict__ logits) {
    int r = blockIdx.x;
    int j = threadIdx.x;
    __shared__ int sidx[NFF];
    __shared__ float sx[2];
    __shared__ float red[256];
    const float* xr = x + (size_t)r * F35;
    if (j < 2) sx[j] = xr[j];
    if (j >= 2 && j < F35) sidx[j - 2] = (int)xr[j];
    __syncthreads();
    const float* w = W1 + (size_t)j * K1;
    float acc = b1[j];
    float s0 = 0.f, s1 = 0.f;
#pragma unroll
    for (int e = 0; e < 32; ++e) { s0 += w[e]; s1 += w[32 + e]; }
    acc += sx[0] * s0 + sx[1] * s1;
    for (int f = 0; f < NFF; ++f) {
        const float* tr = tables + ((size_t)f * VV + sidx[f]) * EE;
        const float* wf = w + 64 + 32 * f;
#pragma unroll
        for (int e = 0; e < 32; ++e) acc += tr[e] * wf[e];
    }
    float h = fmaxf(acc, 0.f);
    red[j] = h * W2[j];
    __syncthreads();
#pragma unroll
    for (int s = 128; s > 0; s >>= 1) {
        if (j < s) red[j] += red[j + s];
        __syncthreads();
    }
    if (j == 0) logits[r] = red[0] + b2[0];
}

// ---------------- softmax over P per b (in-place on d_out) ----------------
__global__ void k_softmax(float* __restrict__ io) {
    int b = blockIdx.x;
    int t = threadIdx.x;  // 128
    __shared__ float buf[128];
    float v = (t < PP) ? io[(size_t)b * PP + t] : -INFINITY;
    buf[t] = v;
    __syncthreads();
#pragma unroll
    for (int s = 64; s > 0; s >>= 1) {
        if (t < s) buf[t] = fmaxf(buf[t], buf[t + s]);
        __syncthreads();
    }
    float m = buf[0];
    __syncthreads();
    float e = (t < PP) ? __expf(v - m) : 0.f;
    buf[t] = e;
    __syncthreads();
#pragma unroll
    for (int s = 64; s > 0; s >>= 1) {
        if (t < s) buf[t] += buf[t + s];
        __syncthreads();
    }
    float denom = buf[0];
    if (t < PP) io[(size_t)b * PP + t] = e / denom;
}

extern "C" void kernel_launch(void* const* d_in, const int* in_sizes, int n_in,
                              void* d_out, int out_size, void* d_ws, size_t ws_size,
                              hipStream_t stream) {
    const float* x      = (const float*)d_in[0];
    const float* tables = (const float*)d_in[1];
    const float* W1     = (const float*)d_in[2];
    const float* b1     = (const float*)d_in[3];
    const float* W2     = (const float*)d_in[4];
    const float* b2     = (const float*)d_in[5];
    float* out = (float*)d_out;  // logits staged in-place, then softmax in-place

    const size_t gbytes = (size_t)NFF * VV * HH;  // 8,448,000 (fp8), 256B-aligned
    const size_t need = gbytes + 2048;

    if (ws_size >= need) {
        char* ws = (char*)d_ws;
        unsigned char* G = (unsigned char*)ws;
        float* S01 = (float*)(ws + gbytes);
        hipLaunchKernelGGL(k_pre, dim3(NFF * 25 + 1), dim3(256), 0, stream, tables, W1, G, S01);
        hipLaunchKernelGGL(k_main, dim3(BB * PP / 4), dim3(256), 0, stream,
                           x, G, S01, b1, W2, b2, out);
    } else {
        hipLaunchKernelGGL(k_direct, dim3(BB * PP), dim3(256), 0, stream,
                           x, tables, W1, b1, W2, b2, out);
    }
    hipLaunchKernelGGL(k_softmax, dim3(BB), dim3(128), 0, stream, out);
}